// Round 20
// baseline (100.040 us; speedup 1.0000x reference)
//
#include <hip/hip_runtime.h>
#include <hip/hip_bf16.h>

typedef _Float16 f16x8 __attribute__((ext_vector_type(8)));
typedef float f32x4  __attribute__((ext_vector_type(4)));
typedef __fp16 fp16x2 __attribute__((ext_vector_type(2)));

#define NB 512
#define NN 256
#define ND 128
#define H_STRIDE 136    // s_h row stride (f16 elems)
#define VT_STRIDE 40    // s_vt row stride (32 j + pad, 16B-aligned rows)
#define SMEM_SHORTS (NN*H_STRIDE + ND*VT_STRIDE + 4*ND)
#define SMEM_BYTES (SMEM_SHORTS * 2)   // 80,896 B = 79 KB -> 2 blocks/CU

__device__ __forceinline__ unsigned pack_f16(float a, float b) {
    union { fp16x2 v; unsigned u; } x;
    x.v = __builtin_amdgcn_cvt_pkrtz(a, b);     // v_cvt_pkrtz_f16_f32
    return x.u;
}
__device__ __forceinline__ float unp_lo(unsigned u) {
    union { unsigned short s; __fp16 h; } x; x.s = (unsigned short)(u & 0xffffu);
    return (float)x.h;
}
__device__ __forceinline__ float unp_hi(unsigned u) {
    union { unsigned short s; __fp16 h; } x; x.s = (unsigned short)(u >> 16);
    return (float)x.h;
}

__global__ __attribute__((amdgpu_flat_work_group_size(512, 512)))
__attribute__((amdgpu_waves_per_eu(2, 4)))
void gat_fused(const float* __restrict__ hidden, const int* __restrict__ adj,
               const float* __restrict__ a0, const float* __restrict__ a1,
               const float* __restrict__ a2, const float* __restrict__ a3,
               float* __restrict__ out)
{
    extern __shared__ short smem[];
    short* s_h  = smem;                      // [256][136] f16, row-major h
    short* s_vt = s_h + NN * H_STRIDE;       // [128][40] f16, per-phase h^T tile
    short* s_a  = s_vt + ND * VT_STRIDE;     // [4][128] f16 a_r

    const int b    = blockIdx.x;
    const int tid  = threadIdx.x;
    const int wave = tid >> 6;               // 0..7
    const int lane = tid & 63;
    const int c = lane & 15;   // fragment column index (lane&15)
    const int g = lane >> 4;   // k-group (lane>>4)

    // srclanes for PV A-fragment gather: target j = 32ph + 8g + 2r -> source (c, g')
    int srcl[4];
    #pragma unroll
    for (int r = 0; r < 4; ++r) srcl[r] = c + 16 * (((8 * g + 2 * r) & 15) >> 2);

    // per-thread transpose task (used every PV phase)
    const int tj  = tid & 31;          // j within phase
    const int td0 = (tid >> 5) * 8;    // d block of 8

    // ---- phase A: global -> s_h (coalesced float4, pk f16 cvt, b64 writes) ----
    const float* hb = hidden + (size_t)b * (NN * ND);
    for (int idx = tid * 4; idx < NN * ND; idx += 512 * 4) {
        const float4 v = *(const float4*)(hb + idx);
        const int j = idx >> 7, d = idx & (ND - 1);
        uint2 pkv;
        pkv.x = pack_f16(v.x, v.y);
        pkv.y = pack_f16(v.z, v.w);
        *(uint2*)&s_h[j * H_STRIDE + d] = pkv;
    }
    {   // a_r -> LDS (512 threads cover 4x128 exactly)
        const float* ap = (tid < 128) ? a0 : (tid < 256) ? a1 : (tid < 384) ? a2 : a3;
        union { __fp16 h; short s; } cv; cv.h = (__fp16)ap[tid & 127];
        s_a[tid] = cv.s;
    }
    __syncthreads();

    const int* adj_b = adj + ((size_t)b << 16);
    float* out_b = out + (size_t)b * (NN * ND);

    for (int n = 0; n < 2; ++n) {
        const int it = wave + 8 * n;
        const int ibase = it * 16;

        // ---- adj for this i-tile, 4-bit packed: 8 VGPRs, read ONCE ----
        unsigned avpk4[8];
        #pragma unroll
        for (int jt2 = 0; jt2 < 8; ++jt2) {
            const int4 aA = *(const int4*)&adj_b[(ibase + c) * NN + (2 * jt2) * 16 + 4 * g];
            const int4 aB = *(const int4*)&adj_b[(ibase + c) * NN + (2 * jt2 + 1) * 16 + 4 * g];
            avpk4[jt2] = (unsigned)aA.x | ((unsigned)aA.y << 4) |
                         ((unsigned)aA.z << 8) | ((unsigned)aA.w << 12) |
                         ((unsigned)aB.x << 16) | ((unsigned)aB.y << 20) |
                         ((unsigned)aB.z << 24) | ((unsigned)aB.w << 28);
        }
        __builtin_amdgcn_sched_barrier(0);

        unsigned scp[16][2];   // pass A: packed f16 raw scores; pass B: packed f16 P
        float sum = 0.f;       // skip-max softmax: scores bounded (|s|<~9), exp safe

        // ===== pass A: relations 1,2 (weights a0,a1); raw scores, f16-packed =====
        {
            f16x8 qs[2][4];
            #pragma unroll
            for (int s = 0; s < 4; ++s) {
                const f16x8 q = *(const f16x8*)&s_h[(ibase + c) * H_STRIDE + s * 32 + g * 8];
                #pragma unroll
                for (int r = 0; r < 2; ++r) {
                    const f16x8 av = *(const f16x8*)&s_a[r * ND + s * 32 + g * 8];
                    qs[r][s] = q * av;               // v_pk_mul_f16 x4
                }
            }
            #pragma unroll
            for (int jt = 0; jt < 16; ++jt) {
                if ((jt & 1) == 0) __builtin_amdgcn_sched_barrier(0);  // cap hoisting
                const int jbase = jt * 16;
                f32x4 e0 = {0.f,0.f,0.f,0.f}, e1 = {0.f,0.f,0.f,0.f};
                __builtin_amdgcn_s_setprio(1);
                #pragma unroll
                for (int s = 0; s < 4; ++s) {
                    const f16x8 hj = *(const f16x8*)&s_h[(jbase + c) * H_STRIDE + s * 32 + g * 8];
                    e0 = __builtin_amdgcn_mfma_f32_16x16x32_f16(hj, qs[0][s], e0, 0, 0, 0);
                    e1 = __builtin_amdgcn_mfma_f32_16x16x32_f16(hj, qs[1][s], e1, 0, 0, 0);
                }
                __builtin_amdgcn_s_setprio(0);
                const unsigned apk = avpk4[jt >> 1] >> ((jt & 1) * 16);
                float v[4];
                #pragma unroll
                for (int q = 0; q < 4; ++q) {
                    const int a = (apk >> (4 * q)) & 0xf;
                    v[q] = (a == 1) ? e0[q] : (a == 2) ? e1[q] : -9.0e15f;  // f16 RTZ clamps to -65504
                }
                scp[jt][0] = pack_f16(v[0], v[1]);
                scp[jt][1] = pack_f16(v[2], v[3]);
            }
        }

        // ===== pass B: relations 3,4; select+leaky, inline exp+sum, store P =====
        {
            f16x8 qs[2][4];
            #pragma unroll
            for (int s = 0; s < 4; ++s) {
                const f16x8 q = *(const f16x8*)&s_h[(ibase + c) * H_STRIDE + s * 32 + g * 8];
                #pragma unroll
                for (int r = 0; r < 2; ++r) {
                    const f16x8 av = *(const f16x8*)&s_a[(r + 2) * ND + s * 32 + g * 8];
                    qs[r][s] = q * av;               // v_pk_mul_f16 x4
                }
            }
            #pragma unroll
            for (int jt = 0; jt < 16; ++jt) {
                if ((jt & 1) == 0) __builtin_amdgcn_sched_barrier(0);  // cap hoisting
                const int jbase = jt * 16;
                f32x4 e2 = {0.f,0.f,0.f,0.f}, e3 = {0.f,0.f,0.f,0.f};
                __builtin_amdgcn_s_setprio(1);
                #pragma unroll
                for (int s = 0; s < 4; ++s) {
                    const f16x8 hj = *(const f16x8*)&s_h[(jbase + c) * H_STRIDE + s * 32 + g * 8];
                    e2 = __builtin_amdgcn_mfma_f32_16x16x32_f16(hj, qs[0][s], e2, 0, 0, 0);
                    e3 = __builtin_amdgcn_mfma_f32_16x16x32_f16(hj, qs[1][s], e3, 0, 0, 0);
                }
                __builtin_amdgcn_s_setprio(0);
                const unsigned apk = avpk4[jt >> 1] >> ((jt & 1) * 16);
                float p[4];
                #pragma unroll
                for (int q = 0; q < 4; ++q) {
                    const int a = (apk >> (4 * q)) & 0xf;
                    const float prev = (q == 0) ? unp_lo(scp[jt][0]) :
                                       (q == 1) ? unp_hi(scp[jt][0]) :
                                       (q == 2) ? unp_lo(scp[jt][1]) : unp_hi(scp[jt][1]);
                    float e = (a == 3) ? e2[q] : (a == 4) ? e3[q] : prev;
                    e = e > 0.f ? e : 0.2f * e;   // leaky; masked -> huge negative -> exp=0
                    p[q] = __expf(e);             // no max subtraction (bounded scores)
                    sum += p[q];
                }
                scp[jt][0] = pack_f16(p[0], p[1]);
                scp[jt][1] = pack_f16(p[2], p[3]);
            }
        }

        // ===== softmax denominator: reduce sum; gather 1/sum to row owners =====
        sum += __shfl_xor(sum, 16);
        sum += __shfl_xor(sum, 32);
        const float rinv = 1.f / sum;
        float rq[4];
        #pragma unroll
        for (int q = 0; q < 4; ++q) rq[q] = __shfl(rinv, 4 * g + q, 64);

        // ===== PV: per-phase cooperative transpose into s_vt, then MFMA =====
        f32x4 oacc[8];
        #pragma unroll
        for (int dt = 0; dt < 8; ++dt) oacc[dt] = (f32x4){0.f,0.f,0.f,0.f};
        #pragma unroll
        for (int ph = 0; ph < 8; ++ph) {
            __syncthreads();   // WAR: prior phase's s_vt reads complete
            {   // transpose h rows [32ph, 32ph+32) -> s_vt[d][j]
                union { short s[8]; uint4 u; } tk;
                tk.u = *(const uint4*)&s_h[(ph * 32 + tj) * H_STRIDE + td0];
                #pragma unroll
                for (int e = 0; e < 8; ++e)
                    s_vt[(td0 + e) * VT_STRIDE + tj] = tk.s[e];
            }
            // P A-fragment via shfl (register-only w.r.t. s_vt)
            union { unsigned u[4]; f16x8 v; } pa;
            #pragma unroll
            for (int r = 0; r < 4; ++r) {
                const unsigned lo = __shfl(scp[2 * ph][r & 1], srcl[r], 64);
                const unsigned hi = __shfl(scp[2 * ph + 1][r & 1], srcl[r], 64);
                pa.u[r] = (g >= 2) ? hi : lo;
            }
            __syncthreads();   // RAW: s_vt ready
            __builtin_amdgcn_s_setprio(1);
            #pragma unroll
            for (int dt = 0; dt < 8; ++dt) {
                const f16x8 vb = *(const f16x8*)&s_vt[(dt * 16 + c) * VT_STRIDE + g * 8];
                oacc[dt] = __builtin_amdgcn_mfma_f32_16x16x32_f16(pa.v, vb, oacc[dt], 0, 0, 0);
            }
            __builtin_amdgcn_s_setprio(0);
        }

        // ===== epilogue: scale by 1/sum (per output row) and store fp32 =====
        #pragma unroll
        for (int dt = 0; dt < 8; ++dt)
            #pragma unroll
            for (int q = 0; q < 4; ++q)
                out_b[(ibase + 4 * g + q) * ND + dt * 16 + c] = oacc[dt][q] * rq[q];
    }
}

extern "C" void kernel_launch(void* const* d_in, const int* in_sizes, int n_in,
                              void* d_out, int out_size, void* d_ws, size_t ws_size,
                              hipStream_t stream) {
    const float* hidden = (const float*)d_in[0];
    const int*   adjp   = (const int*)d_in[1];
    const float* a0 = (const float*)d_in[2];
    const float* a1 = (const float*)d_in[3];
    const float* a2 = (const float*)d_in[4];
    const float* a3 = (const float*)d_in[5];
    float* outp = (float*)d_out;

    (void)hipFuncSetAttribute((const void*)gat_fused,
                              hipFuncAttributeMaxDynamicSharedMemorySize, SMEM_BYTES);
    gat_fused<<<dim3(NB), dim3(512), SMEM_BYTES, stream>>>(hidden, adjp, a0, a1, a2, a3, outp);
}